// Round 5
// baseline (5203.814 us; speedup 1.0000x reference)
//
#include <hip/hip_runtime.h>
#include <hip/hip_bf16.h>
#include <cstdint>

typedef __hip_bfloat16 bf16;
typedef unsigned short u16;

__device__ __forceinline__ float tofloat(float x){ return x; }
__device__ __forceinline__ float tofloat(bf16 x){ return __bfloat162float(x); }

static inline int divup(long a, long b){ return (int)((a + b - 1) / b); }

// ---------------- input dtype detection -------------------------------------
// fp32 buffers: low-mantissa u16 halves have bits[14:7]==0xFF w.p. ~1/256.
// Genuine bf16 N(0,1) never has exponent 0xFF. flag>0 <=> inputs are fp32.
__global__ void zero_int(int* p){ *p = 0; }

__global__ void detect_f32(const u16* __restrict__ h, long n, int* flag)
{
    long i = (long)blockIdx.x * blockDim.x + threadIdx.x;
    long st = (long)gridDim.x * blockDim.x;
    int c = 0;
    for (; i < n; i += st)
        if (((h[i] >> 7) & 0xFF) == 0xFF) c++;
    if (c) atomicAdd(flag, c);
}

__global__ void conv_in(const void* __restrict__ src, float* __restrict__ dst,
                        long n, const int* __restrict__ flagp)
{
    bool f32 = (*flagp != 0);
    long i = (long)blockIdx.x * blockDim.x + threadIdx.x;
    long st = (long)gridDim.x * blockDim.x;
    for (; i < n; i += st)
        dst[i] = f32 ? ((const float*)src)[i] : tofloat(((const bf16*)src)[i]);
}

// ---------------- generic tiled GEMM: C[M,N] = A[M,K] @ B[K,N], fp32 --------
// AM: 0 = A fp32, 2 = A dual (runtime flag). B fp32. batch via blockIdx.z.
template<int AM>
__global__ void gemm32(const void* __restrict__ A_, int lda,
                       const float* __restrict__ B, int ldb,
                       float* __restrict__ C, int ldc,
                       int M, int N, int K, long sB, long sC,
                       const int* __restrict__ flagp)
{
    bool af32 = (AM == 0);
    if (AM == 2) af32 = (*flagp != 0);
    const float* Af = (const float*)A_;
    const bf16*  Ab = (const bf16*)A_;
    const float* Bp = B + (long)blockIdx.z * sB;
    float*       Cp = C + (long)blockIdx.z * sC;
    __shared__ float As[32][17];
    __shared__ float Bs[16][33];
    int tx = threadIdx.x, ty = threadIdx.y;
    int tid = ty * 16 + tx;
    int row0 = blockIdx.x * 32, col0 = blockIdx.y * 32;
    float acc00 = 0.f, acc01 = 0.f, acc10 = 0.f, acc11 = 0.f;
    for (int k0 = 0; k0 < K; k0 += 16) {
        {
            int i = tid >> 4, k = tid & 15;
#pragma unroll
            for (int h = 0; h < 2; h++) {
                int r = row0 + i + h * 16, kk = k0 + k;
                float v = 0.f;
                if (r < M && kk < K) {
                    long idx = (long)r * lda + kk;
                    v = af32 ? Af[idx] : tofloat(Ab[idx]);
                }
                As[i + h * 16][k] = v;
            }
        }
        {
            int k = tid >> 5, j = tid & 31;
#pragma unroll
            for (int h = 0; h < 2; h++) {
                int kk = k0 + k + h * 8, c = col0 + j;
                Bs[k + h * 8][j] = (kk < K && c < N) ? Bp[(long)kk * ldb + c] : 0.f;
            }
        }
        __syncthreads();
#pragma unroll
        for (int k = 0; k < 16; k++) {
            float a0 = As[ty][k], a1 = As[ty + 16][k];
            float b0 = Bs[k][tx], b1 = Bs[k][tx + 16];
            acc00 += a0 * b0; acc01 += a0 * b1;
            acc10 += a1 * b0; acc11 += a1 * b1;
        }
        __syncthreads();
    }
    int r0 = row0 + ty, r1 = r0 + 16, c0 = col0 + tx, c1 = c0 + 16;
    if (r0 < M) { if (c0 < N) Cp[(long)r0 * ldc + c0] = acc00;
                  if (c1 < N) Cp[(long)r0 * ldc + c1] = acc01; }
    if (r1 < M) { if (c0 < N) Cp[(long)r1 * ldc + c0] = acc10;
                  if (c1 < N) Cp[(long)r1 * ldc + c1] = acc11; }
}

// ---------------- utility ---------------------------------------------------
__global__ void fillf(float* p, long n, float v)
{
    long i = (long)blockIdx.x * blockDim.x + threadIdx.x;
    long st = (long)gridDim.x * blockDim.x;
    for (; i < n; i += st) p[i] = v;
}

// ---------------- batch-norm (per-column, gamma=1 beta=0) -------------------
__global__ void colstats(const float* __restrict__ X, int M, int N,
                         float* __restrict__ s1, float* __restrict__ s2)
{
    int j = threadIdx.x;
    if (j >= N) return;
    int rows = (M + gridDim.x - 1) / gridDim.x;
    int r0 = blockIdx.x * rows;
    int r1 = min(M, r0 + rows);
    float a = 0.f, b = 0.f;
    for (int i = r0; i < r1; i++) {
        float v = X[(long)i * N + j];
        a += v; b += v * v;
    }
    atomicAdd(&s1[j], a);
    atomicAdd(&s2[j], b);
}

__global__ void bn_finalize(float* s1, float* s2, int N, int M)
{
    int j = blockIdx.x * blockDim.x + threadIdx.x;
    if (j >= N) return;
    float mean = s1[j] / (float)M;
    float var  = fmaxf(s2[j] / (float)M - mean * mean, 0.f);
    s1[j] = mean;
    s2[j] = rsqrtf(var + 1e-5f);
}

__global__ void bn_apply(float* X, long total, int mask,
                         const float* __restrict__ s1, const float* __restrict__ s2,
                         int relu)
{
    long i = (long)blockIdx.x * blockDim.x + threadIdx.x;
    long st = (long)gridDim.x * blockDim.x;
    for (; i < total; i += st) {
        int j = (int)(i & mask);
        float y = (X[i] - s1[j]) * s2[j];
        if (relu) y = fmaxf(y, 0.f);
        X[i] = y;
    }
}

// BN+ReLU fp32 chunk [M, maskc+1] -> fp32 dst[n*ldout + c0 + f]
__global__ void bn_chunk_out(const float* __restrict__ X, long total, int lgc, int maskc,
                             const float* __restrict__ s1, const float* __restrict__ s2,
                             float* __restrict__ dst, int ldout, int c0)
{
    long i = (long)blockIdx.x * blockDim.x + threadIdx.x;
    long st = (long)gridDim.x * blockDim.x;
    for (; i < total; i += st) {
        long n = i >> lgc;
        int  f = (int)(i & maskc);
        float y = fmaxf((X[i] - s1[f]) * s2[f], 0.f);
        dst[n * ldout + c0 + f] = y;
    }
}

// ---------------- GCN pieces ------------------------------------------------
__global__ void deg_count(const int* __restrict__ dst, long E, float* deg)
{
    long i = (long)blockIdx.x * blockDim.x + threadIdx.x;
    long st = (long)gridDim.x * blockDim.x;
    for (; i < E; i += st) atomicAdd(&deg[dst[i]], 1.0f);
}

__global__ void rsqrt_inplace(float* p, long n)
{
    long i = (long)blockIdx.x * blockDim.x + threadIdx.x;
    long st = (long)gridDim.x * blockDim.x;
    for (; i < n; i += st) p[i] = rsqrtf(fmaxf(p[i], 1.0f));
}

__global__ void gcn_self(const float* __restrict__ h, const float* __restrict__ dinv,
                         float* __restrict__ out, long total, int lg)
{
    long i = (long)blockIdx.x * blockDim.x + threadIdx.x;
    long st = (long)gridDim.x * blockDim.x;
    for (; i < total; i += st) {
        int node = (int)(i >> lg);
        float dv = dinv[node];
        out[i] = h[i] * dv * dv;
    }
}

__global__ void gcn_edge(const float* __restrict__ h, const float* __restrict__ dinv,
                         const int* __restrict__ src, const int* __restrict__ dst,
                         long total, int lg, int mask, float* __restrict__ out)
{
    long i = (long)blockIdx.x * blockDim.x + threadIdx.x;
    long st = (long)gridDim.x * blockDim.x;
    for (; i < total; i += st) {
        long e = i >> lg;
        int  f = (int)(i & mask);
        int s = src[e], d = dst[e];
        float nrm = dinv[s] * dinv[d];
        atomicAdd(&out[((long)d << lg) + f], h[((long)s << lg) + f] * nrm);
    }
}

// ---------------- pooling ---------------------------------------------------
__global__ void pool_cnt(const int* __restrict__ batch, long n, float* cnt)
{
    long i = (long)blockIdx.x * blockDim.x + threadIdx.x;
    long st = (long)gridDim.x * blockDim.x;
    for (; i < n; i += st) atomicAdd(&cnt[batch[i]], 1.0f);
}

__global__ void pool_sum_chunk(const float* __restrict__ g, const int* __restrict__ batch,
                               long total, int lgc, int maskc,
                               float* __restrict__ sums, int ldout, int c0)
{
    long i = (long)blockIdx.x * blockDim.x + threadIdx.x;
    long st = (long)gridDim.x * blockDim.x;
    for (; i < total; i += st) {
        long n = i >> lgc;
        int  f = (int)(i & maskc);
        atomicAdd(&sums[(long)batch[n] * ldout + c0 + f], g[i]);
    }
}

__global__ void pool_div(float* sums, const float* __restrict__ cnt, long total, int lg)
{
    long i = (long)blockIdx.x * blockDim.x + threadIdx.x;
    long st = (long)gridDim.x * blockDim.x;
    for (; i < total; i += st) sums[i] /= fmaxf(cnt[i >> lg], 1.0f);
}

// ---------------- attention fusion (one 128-thread block per drug) ----------
__global__ void attention_fuse(const float* __restrict__ go, const float* __restrict__ fpv,
                               const float* __restrict__ W1, const float* __restrict__ B1,
                               const float* __restrict__ W2,
                               float* __restrict__ emb, float* __restrict__ beta_out)
{
    int d = blockIdx.x;
    int t = threadIdx.x;                 // 128 threads
    __shared__ float z[2][256];
    __shared__ float red[128];
    for (int c = t; c < 256; c += 128) {
        z[0][c] = go[(long)d * 256 + c];
        z[1][c] = fpv[(long)d * 256 + c];
    }
    __syncthreads();
    float s[2];
    for (int v = 0; v < 2; v++) {
        float acc = B1[t];
        for (int k = 0; k < 256; k++) acc += z[v][k] * W1[k * 128 + t];
        red[t] = tanhf(acc) * W2[t];
        __syncthreads();
        for (int off = 64; off > 0; off >>= 1) {
            if (t < off) red[t] += red[t + off];
            __syncthreads();
        }
        s[v] = red[0];
        __syncthreads();
    }
    float m = fmaxf(s[0], s[1]);
    float e0 = expf(s[0] - m), e1 = expf(s[1] - m);
    float inv = 1.0f / (e0 + e1);
    float b0 = e0 * inv, b1 = e1 * inv;
    for (int c = t; c < 256; c += 128)
        emb[(long)d * 256 + c] = b0 * z[0][c] + b1 * z[1][c];
    if (t == 0) {
        beta_out[d * 2 + 0] = b0;
        beta_out[d * 2 + 1] = b1;
    }
}

// ---------------- RGCN pieces -----------------------------------------------
__global__ void kg_cnt(const int* __restrict__ dst, const int* __restrict__ et,
                       long E, int NKG, float* cnt)
{
    long i = (long)blockIdx.x * blockDim.x + threadIdx.x;
    long st = (long)gridDim.x * blockDim.x;
    for (; i < E; i += st) atomicAdd(&cnt[(long)et[i] * NKG + dst[i]], 1.0f);
}

__global__ void rgcn_edge(const float* __restrict__ hr, const int* __restrict__ src,
                          const int* __restrict__ dst, const int* __restrict__ et,
                          const float* __restrict__ cnt, long total, int lg, int mask,
                          int NKG, float* __restrict__ out, int ldout, int c0)
{
    long i = (long)blockIdx.x * blockDim.x + threadIdx.x;
    long st = (long)gridDim.x * blockDim.x;
    for (; i < total; i += st) {
        long e = i >> lg;
        int  f = (int)(i & mask);
        int r = et[e], s = src[e], d = dst[e];
        float nrm = 1.0f / fmaxf(cnt[(long)r * NKG + d], 1.0f);
        atomicAdd(&out[(long)d * ldout + c0 + f],
                  hr[(((long)r * NKG + s) << lg) + f] * nrm);
    }
}

// ---------------- final linear + log_softmax (fp32 out) ---------------------
__global__ void logits_out(const float* __restrict__ x4, const float* __restrict__ w,
                           const float* __restrict__ b, float* __restrict__ out, int NKG)
{
    int i = blockIdx.x * blockDim.x + threadIdx.x;
    if (i >= NKG) return;
    float a0 = b[0], a1 = b[1];
    for (int k = 0; k < 64; k++) {
        float v = x4[(long)i * 64 + k];
        a0 += v * w[k * 2 + 0];
        a1 += v * w[k * 2 + 1];
    }
    float m = fmaxf(a0, a1);
    float lse = m + logf(expf(a0 - m) + expf(a1 - m));
    out[i * 2 + 0] = a0 - lse;
    out[i * 2 + 1] = a1 - lse;
}

// ============================================================================
extern "C" void kernel_launch(void* const* d_in, const int* in_sizes, int n_in,
                              void* d_out, int out_size, void* d_ws, size_t ws_size,
                              hipStream_t stream)
{
    (void)in_sizes; (void)n_in; (void)out_size; (void)ws_size;
    const int ND = 4096, NM = 131072, NKG = 9510, NGENE = 5414;
    const long EM = 524288, EK = 524288;

    const void* fp_data = d_in[0];
    const void* mol_x   = d_in[1];
    const int*  mol_batch = (const int*)d_in[2];
    const int*  mol_ei  = (const int*)d_in[3];
    const int*  kg_ei   = (const int*)d_in[4];
    const int*  kg_et   = (const int*)d_in[5];

    const int* mol_src = mol_ei;
    const int* mol_dst = mol_ei + EM;
    const int* kg_src  = kg_ei;
    const int* kg_dst  = kg_ei + EK;

    float* out_ls   = (float*)d_out;          // [9510,2] fp32
    float* out_beta = (float*)d_out + 19020;  // [4096,2,1] fp32

    // ---- workspace carve (~113.5 MB; big region time-shared) ----
    char* wp = (char*)d_ws;
    auto carve = [&](size_t bytes) { char* p = wp; wp += (bytes + 255) & ~(size_t)255; return p; };
    float* stats = (float*)carve(4096);                    // s1 | s2 at +512
    int*   flag  = (int*)carve(256);
    float* dinv  = (float*)carve((size_t)NM * 4);          // 0.5 MB
    float* cntP  = (float*)carve((size_t)ND * 4);
    float* cntK  = (float*)carve((size_t)8 * NKG * 4);     // 0.3 MB
    float* Wpool = (float*)carve((size_t)1630000 * 4);     // 6.5 MB fp32 weights
    float* fpb   = (float*)carve((size_t)ND * 256 * 4);    // 4.2 MB
    float* gout  = (float*)carve((size_t)ND * 256 * 4);    // 4.2 MB
    float* G1REG = (float*)carve((size_t)NM * 128 * 4);    // 64 MB time-shared
    float* BIG   = (float*)carve((size_t)NM * 32 * 4);     // 16.8 MB scatter chunk
    float* HB    = (float*)carve((size_t)NM * 32 * 4);     // 16.8 MB GEMM-out chunk

    // G1REG phase views (phases strictly sequential):
    float* fp1 = G1REG;                       // [4096,512] fp phase (8 MB)
    float* G1  = G1REG;                       // [NM,128]   mol phase (64 MB)
    float* xkg = G1REG;                       // RGCN phase (36.5 MB total)
    float* x2  = xkg + (size_t)NKG * 256;
    float* x3  = x2  + (size_t)NKG * 256;
    float* x4  = x3  + (size_t)NKG * 128;
    float* HR  = x4  + (size_t)NKG * 64;      // [8,NKG,32] fp32

    dim3 tb(16, 16);
    const int SCAT = 8192;
    const int WM = 32, LGM = 5, MSKM = 31;    // mol col-chunk
    const int WK = 32, LGK = 5, MSKK = 31;    // rgcn col-chunk

    // ---- dtype detection + parameter conversion to fp32 ----
    zero_int<<<1, 1, 0, stream>>>(flag);
    detect_f32<<<1024, 256, 0, stream>>>((const u16*)fp_data, (long)ND * 1024, flag);
    size_t woff = 0;
    auto conv = [&](int idx, long n) {
        float* dst = Wpool + woff; woff += (size_t)n;
        conv_in<<<256, 256, 0, stream>>>(d_in[idx], dst, n, flag);
        return dst;
    };
    float* fp_w1c   = conv(6,  1024L * 512);
    float* fp_w2c   = conv(8,  512L * 256);
    float* gcn_w1c  = conv(10, 64L * 128);
    float* gcn_w2c  = conv(12, 128L * 256);
    float* att_w1c  = conv(14, 256L * 128);
    float* att_b1c  = conv(15, 128);
    float* att_w2c  = conv(16, 128);
    float* rg_w1c   = conv(18, 8L * 256 * 256);
    float* rg_root1c= conv(19, 256L * 256);
    float* rg_w2c   = conv(21, 8L * 256 * 128);
    float* rg_root2c= conv(22, 256L * 128);
    float* lin1_wc  = conv(24, 128L * 64);
    float* lin2_wc  = conv(26, 64L * 2);
    float* lin2_bc  = conv(27, 2);

    auto bn_stats = [&](const float* X, int M, int N) {
        fillf<<<4, 256, 0, stream>>>(stats, 1024, 0.f);
        colstats<<<256, N, 0, stream>>>(X, M, N, stats, stats + 512);
        bn_finalize<<<2, 256, 0, stream>>>(stats, stats + 512, N, M);
    };
    auto batchnorm = [&](float* X, int M, int N, int relu) {
        bn_stats(X, M, N);
        long total = (long)M * N;
        int g = divup(total, 256); if (g > 16384) g = 16384;
        bn_apply<<<g, 256, 0, stream>>>(X, total, N - 1, stats, stats + 512, relu);
    };

    // ---------- fingerprint MLP branch ----------
    gemm32<2><<<dim3(divup(ND,32), 16, 1), tb, 0, stream>>>(
        fp_data, 1024, fp_w1c, 512, fp1, 512, ND, 512, 1024, 0, 0, flag);
    batchnorm(fp1, ND, 512, 1);
    gemm32<0><<<dim3(divup(ND,32), 8, 1), tb, 0, stream>>>(
        fp1, 512, fp_w2c, 256, fpb, 256, ND, 256, 512, 0, 0, nullptr);
    batchnorm(fpb, ND, 256, 1);

    // ---------- molecular GCN branch ----------
    fillf<<<512, 256, 0, stream>>>(dinv, NM, 1.0f);      // self-loop degree
    deg_count<<<2048, 256, 0, stream>>>(mol_dst, EM, dinv);
    rsqrt_inplace<<<512, 256, 0, stream>>>(dinv, NM);

    // layer 1: out width 128, WM-col chunks -> G1 fp32  [fp1 dead after fpb]
    for (int c0 = 0; c0 < 128; c0 += WM) {
        gemm32<2><<<dim3(divup(NM,32), 1, 1), tb, 0, stream>>>(
            mol_x, 64, gcn_w1c + c0, 128, HB, WM, NM, WM, 64, 0, 0, flag);
        gcn_self<<<SCAT, 256, 0, stream>>>(HB, dinv, BIG, (long)NM * WM, LGM);
        gcn_edge<<<SCAT, 256, 0, stream>>>(HB, dinv, mol_src, mol_dst, EM * WM, LGM, MSKM, BIG);
        bn_stats(BIG, NM, WM);
        bn_chunk_out<<<SCAT, 256, 0, stream>>>(BIG, (long)NM * WM, LGM, MSKM,
                                               stats, stats + 512, G1, 128, c0);
    }

    // layer 2: out width 256, WM-col chunks -> pooled gout
    fillf<<<512, 256, 0, stream>>>(gout, (long)ND * 256, 0.f);
    fillf<<<16, 256, 0, stream>>>(cntP, ND, 0.f);
    pool_cnt<<<512, 256, 0, stream>>>(mol_batch, NM, cntP);
    for (int c0 = 0; c0 < 256; c0 += WM) {
        gemm32<0><<<dim3(divup(NM,32), 1, 1), tb, 0, stream>>>(
            G1, 128, gcn_w2c + c0, 256, HB, WM, NM, WM, 128, 0, 0, nullptr);
        gcn_self<<<SCAT, 256, 0, stream>>>(HB, dinv, BIG, (long)NM * WM, LGM);
        gcn_edge<<<SCAT, 256, 0, stream>>>(HB, dinv, mol_src, mol_dst, EM * WM, LGM, MSKM, BIG);
        bn_stats(BIG, NM, WM);
        bn_apply<<<16384, 256, 0, stream>>>(BIG, (long)NM * WM, MSKM, stats, stats + 512, 1);
        pool_sum_chunk<<<SCAT, 256, 0, stream>>>(BIG, mol_batch, (long)NM * WM, LGM, MSKM,
                                                 gout, 256, c0);
    }
    pool_div<<<1024, 256, 0, stream>>>(gout, cntP, (long)ND * 256, 8);

    // ---------- attention fusion (emb -> xkg rows [0,ND))  [G1 dead] --------
    attention_fuse<<<ND, 128, 0, stream>>>(gout, fpb, att_w1c, att_b1c, att_w2c, xkg, out_beta);
    conv_in<<<512, 256, 0, stream>>>(d_in[17], xkg + (long)ND * 256, (long)NGENE * 256, flag);

    // ---------- RGCN layer 1 (256 -> 256) ----------
    fillf<<<128, 256, 0, stream>>>(cntK, (long)8 * NKG, 0.f);
    kg_cnt<<<2048, 256, 0, stream>>>(kg_dst, kg_et, EK, NKG, cntK);
    gemm32<0><<<dim3(divup(NKG,32), 8, 1), tb, 0, stream>>>(
        xkg, 256, rg_root1c, 256, x2, 256, NKG, 256, 256, 0, 0, nullptr);
    for (int c0 = 0; c0 < 256; c0 += WK) {
        gemm32<0><<<dim3(divup(NKG,32), 1, 8), tb, 0, stream>>>(
            xkg, 256, rg_w1c + c0, 256, HR, WK, NKG, WK, 256,
            (long)256 * 256, (long)NKG * WK, nullptr);
        rgcn_edge<<<SCAT, 256, 0, stream>>>(HR, kg_src, kg_dst, kg_et, cntK,
                                            EK * WK, LGK, MSKK, NKG, x2, 256, c0);
    }
    batchnorm(x2, NKG, 256, 1);

    // ---------- RGCN layer 2 (256 -> 128) ----------
    gemm32<0><<<dim3(divup(NKG,32), 4, 1), tb, 0, stream>>>(
        x2, 256, rg_root2c, 128, x3, 128, NKG, 128, 256, 0, 0, nullptr);
    for (int c0 = 0; c0 < 128; c0 += WK) {
        gemm32<0><<<dim3(divup(NKG,32), 1, 8), tb, 0, stream>>>(
            x2, 256, rg_w2c + c0, 128, HR, WK, NKG, WK, 256,
            (long)256 * 128, (long)NKG * WK, nullptr);
        rgcn_edge<<<SCAT, 256, 0, stream>>>(HR, kg_src, kg_dst, kg_et, cntK,
                                            EK * WK, LGK, MSKK, NKG, x3, 128, c0);
    }
    batchnorm(x3, NKG, 128, 1);

    // ---------- classifier head ----------
    gemm32<0><<<dim3(divup(NKG,32), 2, 1), tb, 0, stream>>>(
        x3, 128, lin1_wc, 64, x4, 64, NKG, 64, 128, 0, 0, nullptr);
    batchnorm(x4, NKG, 64, 1);
    logits_out<<<divup(NKG, 256), 256, 0, stream>>>(x4, lin2_wc, lin2_bc, out_ls, NKG);
}